// Round 8
// baseline (89.877 us; speedup 1.0000x reference)
//
#include <hip/hip_runtime.h>

// Problem constants (match reference)
#define HWPX (512*512)      // pixels per batch
#define NB 2                // batches
#define NL 512              // EH*EW light directions
#define PXPT 4              // 4 pixels (2 packed pairs) per thread
constexpr float PI_F = 3.14159265358979323846f;

typedef float f2 __attribute__((ext_vector_type(2)));

// ---- forced VOP3P packed-f32 ops (clang scalarizes f2 arithmetic: R5/R6 evidence).
// op_sel trick: op_sel:[..]=lo-half word select, op_sel_hi:[..]=hi-half word select.
// Selecting word0 (or word1) for BOTH halves broadcasts one element of the 64-bit
// source pair -> splat with zero v_mov cost, directly from the compact LDS pair.

__device__ __forceinline__ f2 pk_mul(f2 a, f2 b) {
    f2 d; asm("v_pk_mul_f32 %0, %1, %2" : "=v"(d) : "v"(a), "v"(b)); return d;
}
// a * splat(q.x)
__device__ __forceinline__ f2 pk_mul_s0(f2 a, f2 q) {
    f2 d; asm("v_pk_mul_f32 %0, %1, %2 op_sel:[0,0] op_sel_hi:[1,0]"
              : "=v"(d) : "v"(a), "v"(q)); return d;
}
// a * splat(q.x) + c
__device__ __forceinline__ f2 pk_fma_s0(f2 a, f2 q, f2 c) {
    f2 d; asm("v_pk_fma_f32 %0, %1, %2, %3 op_sel:[0,0,0] op_sel_hi:[1,0,1]"
              : "=v"(d) : "v"(a), "v"(q), "v"(c)); return d;
}
// a * splat(q.y) + c
__device__ __forceinline__ f2 pk_fma_s1(f2 a, f2 q, f2 c) {
    f2 d; asm("v_pk_fma_f32 %0, %1, %2, %3 op_sel:[0,1,0] op_sel_hi:[1,1,1]"
              : "=v"(d) : "v"(a), "v"(q), "v"(c)); return d;
}

// ws layout (bytes):
//   [0]      unsigned max-bits slot (f32 >= 0, bit-monotone)
//   [256]    float2 tab[2][512][3] : COMPACT per light: {hx,hy} {hz,e0c} {e1c,e2c}
//            (c = sin(phi)/60 folded into env)
//
// Identity: (relu(s)/max)^64 == relu(s)^64 * (1/max)^64 with |s|<=1 -> accumulate
// UNNORMALIZED, track global max in-pass, k_finalize scales by (1/max)^64.

__global__ void k_setup(const float* __restrict__ env,
                        float2* __restrict__ tab,
                        unsigned* __restrict__ maxslot) {
    int m = threadIdx.x;            // 512 threads, one per light dir
    if (m == 0) *maxslot = 0u;      // re-zeroed every launch (replay-safe)
    int p = m >> 5;                 // phi index (EH=16)
    int t = m & 31;                 // theta index (EW=32)
    float phi = (float)p * (PI_F / 16.0f);
    float th  = (float)t * (2.0f * PI_F / 32.0f);
    float sp = sinf(phi), cp = cosf(phi);
    float st = sinf(th),  ct = cosf(th);
    // l = (st*sp, cp, -ct*sp); h = l + view(0,0,1), normalized
    float hx = st * sp;
    float hy = cp;
    float hz = 1.0f - ct * sp;
    float inv = rsqrtf(hx * hx + hy * hy + hz * hz);
    hx *= inv; hy *= inv; hz *= inv;
    float c = sp * (1.0f / 60.0f);  // solid-angle coeff and the /60 folded in
    #pragma unroll
    for (int b = 0; b < NB; ++b) {
        const float* e = env + ((size_t)(b * NL + m)) * 3;
        float2* dst = tab + (size_t)(b * NL + m) * 3;
        float2 q0; q0.x = hx;       q0.y = hy;
        float2 q1; q1.x = hz;       q1.y = e[0] * c;
        float2 q2; q2.x = e[1] * c; q2.y = e[2] * c;
        dst[0] = q0; dst[1] = q1; dst[2] = q2;
    }
}

__device__ __forceinline__ void load_normal(const float* __restrict__ normal, size_t pix,
                                            float& nx, float& ny, float& nz) {
    const float* p = normal + pix * 3;
    float c0 = p[0], c1 = p[1], c2 = p[2];
    // channel-reversed, [0,1] -> [-1,1], L2 normalize
    float x = (c2 - 0.5f) * 2.0f;
    float y = (c1 - 0.5f) * 2.0f;
    float z = (c0 - 0.5f) * 2.0f;
    float d2 = x * x + y * y + z * z;
    float inv = d2 > 0.0f ? rsqrtf(d2) : 0.0f;
    nx = x * inv; ny = y * inv; nz = z * inv;
}

// PXPT=4 (2 packed pairs), 256 threads -> 512 blocks.
__global__ __launch_bounds__(256) void k_fused(const float* __restrict__ normal,
                                               const float2* __restrict__ tab,
                                               float* __restrict__ out,
                                               unsigned* __restrict__ maxslot) {
    __shared__ float2 sT[NL * 3];                  // 12 KB compact light table
    __shared__ float swmax[4];                     // per-wave partial max

    int bid = blockIdx.x;
    int blocks_per_batch = HWPX / (256 * PXPT);    // 256
    int b = bid / blocks_per_batch;
    int base_in_b = (bid % blocks_per_batch) * (256 * PXPT) + (int)threadIdx.x;

    // stage light table: 768 float4s, 3 per thread, coalesced
    {
        const float4* gp = reinterpret_cast<const float4*>(tab + (size_t)b * NL * 3);
        float4* sp4 = reinterpret_cast<float4*>(sT);
        int t = threadIdx.x;
        #pragma unroll
        for (int j = 0; j < 3; ++j)
            sp4[t + j * 256] = gp[t + j * 256];
    }

    // load 4 normals -> 2 packed pairs
    float nxs[PXPT], nys[PXPT], nzs[PXPT];
    #pragma unroll
    for (int k = 0; k < PXPT; ++k)
        load_normal(normal, (size_t)b * HWPX + base_in_b + k * 256,
                    nxs[k], nys[k], nzs[k]);
    f2 nx2[2], ny2[2], nz2[2];
    #pragma unroll
    for (int k = 0; k < 2; ++k) {
        nx2[k] = f2{nxs[2*k], nxs[2*k+1]};
        ny2[k] = f2{nys[2*k], nys[2*k+1]};
        nz2[k] = f2{nzs[2*k], nzs[2*k+1]};
    }

    __syncthreads();

    f2 a0[2], a1[2], a2[2];
    #pragma unroll
    for (int k = 0; k < 2; ++k) { a0[k] = f2{0,0}; a1[k] = f2{0,0}; a2[k] = f2{0,0}; }
    float mx = 0.0f;

    #pragma unroll 8
    for (int m = 0; m < NL; ++m) {
        float2 q0f = sT[m * 3 + 0];                // {hx,hy}
        float2 q1f = sT[m * 3 + 1];                // {hz,e0}
        float2 q2f = sT[m * 3 + 2];                // {e1,e2}
        f2 q0 = {q0f.x, q0f.y};
        f2 q1 = {q1f.x, q1f.y};
        f2 q2 = {q2f.x, q2f.y};

        #pragma unroll
        for (int k = 0; k < 2; ++k) {
            f2 t  = pk_mul_s0(nz2[k], q1);         // nz * hz
            t     = pk_fma_s1(ny2[k], q0, t);      // + ny * hy
            f2 s  = pk_fma_s0(nx2[k], q0, t);      // + nx * hx
            float sx = fmaxf(s.x, 0.0f);           // relu (no v_pk_max_f32)
            float sy = fmaxf(s.y, 0.0f);
            mx = fmaxf(mx, fmaxf(sx, sy));         // -> v_max3_f32
            f2 r = {sx, sy};
            f2 r2  = pk_mul(r, r);
            f2 r4  = pk_mul(r2, r2);
            f2 r8  = pk_mul(r4, r4);
            f2 r16 = pk_mul(r8, r8);
            f2 r32 = pk_mul(r16, r16);
            f2 r64 = pk_mul(r32, r32);
            a0[k] = pk_fma_s1(r64, q1, a0[k]);     // e0 = q1.y
            a1[k] = pk_fma_s0(r64, q2, a1[k]);     // e1 = q2.x
            a2[k] = pk_fma_s1(r64, q2, a2[k]);     // e2 = q2.y
        }
    }

    // wave-64 max reduce -> LDS -> one atomic per block
    #pragma unroll
    for (int off = 32; off > 0; off >>= 1)
        mx = fmaxf(mx, __shfl_xor(mx, off));
    int wid = threadIdx.x >> 6;
    if ((threadIdx.x & 63) == 0) swmax[wid] = mx;
    __syncthreads();
    if (threadIdx.x == 0) {
        float bm = fmaxf(fmaxf(swmax[0], swmax[1]), fmaxf(swmax[2], swmax[3]));
        atomicMax(maxslot, __float_as_uint(bm));   // f32 >= 0: bit-monotone
    }

    // unnormalized sums to out[b][c][h][w]; finalize scales by (1/max)^64
    float* ob = out + (size_t)b * 3 * HWPX;
    #pragma unroll
    for (int k = 0; k < PXPT; ++k) {
        int p = base_in_b + k * 256;
        f2 v0 = a0[k >> 1], v1 = a1[k >> 1], v2 = a2[k >> 1];
        int h = k & 1;
        ob[0 * HWPX + p] = v0[h];
        ob[1 * HWPX + p] = v1[h];
        ob[2 * HWPX + p] = v2[h];
    }
}

__global__ __launch_bounds__(256) void k_finalize(float* __restrict__ out,
                                                  const unsigned* __restrict__ maxslot) {
    float im  = 1.0f / __uint_as_float(*maxslot);   // uniform scalar load
    float i2  = im * im;
    float i4  = i2 * i2;
    float i8  = i4 * i4;
    float i16 = i8 * i8;
    float i32 = i16 * i16;
    float scl = i32 * i32;                          // (1/max)^64
    int i = blockIdx.x * 256 + (int)threadIdx.x;    // over float4s
    float4* o = reinterpret_cast<float4*>(out);
    float4 v = o[i];
    v.x *= scl; v.y *= scl; v.z *= scl; v.w *= scl;
    o[i] = v;
}

extern "C" void kernel_launch(void* const* d_in, const int* in_sizes, int n_in,
                              void* d_out, int out_size, void* d_ws, size_t ws_size,
                              hipStream_t stream) {
    const float* env    = (const float*)d_in[0];   // (B,16,32,3) f32
    const float* normal = (const float*)d_in[1];   // (B,512,512,3) f32
    float* out = (float*)d_out;                    // (B,3,512,512) f32

    char* ws = (char*)d_ws;
    unsigned* maxslot = (unsigned*)ws;
    float2* tab = (float2*)(ws + 256);

    int nblocks = (NB * HWPX) / (256 * PXPT);      // 512
    int fblocks = (NB * 3 * HWPX) / (4 * 256);     // 1536 (float4 granularity)

    hipLaunchKernelGGL(k_setup, dim3(1), dim3(NL), 0, stream, env, tab, maxslot);
    hipLaunchKernelGGL(k_fused, dim3(nblocks), dim3(256), 0, stream, normal, tab, out, maxslot);
    hipLaunchKernelGGL(k_finalize, dim3(fblocks), dim3(256), 0, stream, out, maxslot);
}

// Round 9
// 75.666 us; speedup vs baseline: 1.1878x; 1.1878x over previous
//
#include <hip/hip_runtime.h>

// Problem constants (match reference)
#define HWPX (512*512)      // pixels per batch
#define NB 2                // batches
#define NL 512              // EH*EW light directions (table rows)
#define NLS 480             // shadeable lights: phi=0 row (32 dirs) has coeff sin(0)=0
#define HNLS 240            // lights per half-block
#define PXPT 4              // pixels per thread
constexpr float PI_F = 3.14159265358979323846f;
constexpr float INV_SQRT2 = 0.70710678118654752f;

typedef float f2 __attribute__((ext_vector_type(2)));

// ws layout (bytes):
//   [0]      unsigned max-bits slot (f32 >= 0, bit-monotone)
//   [256]    float2 tab[2][480][3] : COMPACT per light (phi>=1 rows only):
//            {hx,hy} {hz,e0c} {e1c,e2c}   (c = sin(phi)/60 folded into env)
//
// Identities used:
//  * (relu(s)/max)^64 == relu(s)^64 * (1/max)^64, |s|<=1 -> accumulate
//    UNNORMALIZED, track global max in-pass, finalize scales by (1/max)^64.
//  * phi=0 row: coeff=0 -> contributes nothing to sums (its table entries were
//    exactly 0), only to the max; its dir is h=(0,r2,r2) -> s0=(ny+nz)*r2,
//    seeded analytically.
// R7 lesson: v_pk_f32 does NOT halve VALU cycles on CDNA4 (SIMD-32: packed op
// = 4 cyc vs 2 cyc scalar); scalar code is already at the FLOP floor. This
// round attacks latency exposure: split the LIGHT dim across block halves
// (same pixels), doubling waves/CU at unchanged DS traffic.

__global__ void k_setup(const float* __restrict__ env,
                        float2* __restrict__ tab,
                        unsigned* __restrict__ maxslot) {
    int m = threadIdx.x;            // 512 threads, one per light dir
    if (m == 0) *maxslot = 0u;      // re-zeroed every launch (replay-safe)
    int p = m >> 5;                 // phi index (EH=16)
    int t = m & 31;                 // theta index (EW=32)
    if (p < 1) return;              // phi=0: zero coeff, handled analytically
    float phi = (float)p * (PI_F / 16.0f);
    float th  = (float)t * (2.0f * PI_F / 32.0f);
    float sp = sinf(phi), cp = cosf(phi);
    float st = sinf(th),  ct = cosf(th);
    // l = (st*sp, cp, -ct*sp); h = l + view(0,0,1), normalized
    float hx = st * sp;
    float hy = cp;
    float hz = 1.0f - ct * sp;
    float inv = rsqrtf(hx * hx + hy * hy + hz * hz);
    hx *= inv; hy *= inv; hz *= inv;
    float c = sp * (1.0f / 60.0f);  // solid-angle coeff and the /60 folded in
    int ms = m - 32;                // shadeable index 0..479
    #pragma unroll
    for (int b = 0; b < NB; ++b) {
        const float* e = env + ((size_t)(b * NL + m)) * 3;
        float2* dst = tab + (size_t)(b * NLS + ms) * 3;
        float2 q0; q0.x = hx;       q0.y = hy;
        float2 q1; q1.x = hz;       q1.y = e[0] * c;
        float2 q2; q2.x = e[1] * c; q2.y = e[2] * c;
        dst[0] = q0; dst[1] = q1; dst[2] = q2;
    }
}

__device__ __forceinline__ void load_normal(const float* __restrict__ normal, size_t pix,
                                            float& nx, float& ny, float& nz) {
    const float* p = normal + pix * 3;
    float c0 = p[0], c1 = p[1], c2 = p[2];
    // channel-reversed, [0,1] -> [-1,1], L2 normalize
    float x = (c2 - 0.5f) * 2.0f;
    float y = (c1 - 0.5f) * 2.0f;
    float z = (c0 - 0.5f) * 2.0f;
    float d2 = x * x + y * y + z * z;
    float inv = d2 > 0.0f ? rsqrtf(d2) : 0.0f;
    nx = x * inv; ny = y * inv; nz = z * inv;
}

// 256 threads: halves split the light range, 128 pixel-lanes x PXPT=4 pixels.
// 1024 blocks -> 4 blocks/CU -> 16 waves/CU.
__global__ __launch_bounds__(256) void k_fused(const float* __restrict__ normal,
                                               const float2* __restrict__ tab,
                                               float* __restrict__ out,
                                               unsigned* __restrict__ maxslot) {
    __shared__ float2 sT[NLS * 3];                 // 11.25 KB compact light table
    __shared__ float sMerge[128 * 13];             // 6.5 KB partials (pad 13: no bank conflicts)
    __shared__ float swmax[4];                     // per-wave partial max

    int tid = threadIdx.x;
    int bid = blockIdx.x;
    int blocks_per_batch = HWPX / (128 * PXPT);    // 512
    int b = bid / blocks_per_batch;
    int half = tid >> 7;                           // light-range half
    int li = tid & 127;                            // pixel lane
    int base_in_b = (bid % blocks_per_batch) * (128 * PXPT) + li;

    // stage light table: 720 float4s, coalesced
    {
        const float4* gp = reinterpret_cast<const float4*>(tab + (size_t)b * NLS * 3);
        float4* sp4 = reinterpret_cast<float4*>(sT);
        sp4[tid]       = gp[tid];
        sp4[tid + 256] = gp[tid + 256];
        if (tid < 208) sp4[tid + 512] = gp[tid + 512];
    }

    // load 4 normals -> 2 packed pairs
    float nxs[PXPT], nys[PXPT], nzs[PXPT];
    #pragma unroll
    for (int k = 0; k < PXPT; ++k)
        load_normal(normal, (size_t)b * HWPX + base_in_b + k * 128,
                    nxs[k], nys[k], nzs[k]);
    f2 nx2[2], ny2[2], nz2[2];
    #pragma unroll
    for (int k = 0; k < 2; ++k) {
        nx2[k] = f2{nxs[2*k], nxs[2*k+1]};
        ny2[k] = f2{nys[2*k], nys[2*k+1]};
        nz2[k] = f2{nzs[2*k], nzs[2*k+1]};
    }

    // phi=0 light max seed: h=(0,r2,r2) -> s=(ny+nz)*r2 (only half 0, once)
    float mx = 0.0f;
    if (!half) {
        #pragma unroll
        for (int k = 0; k < PXPT; ++k)
            mx = fmaxf(mx, (nys[k] + nzs[k]) * INV_SQRT2);
    }

    __syncthreads();

    f2 a0[2], a1[2], a2[2];
    #pragma unroll
    for (int k = 0; k < 2; ++k) { a0[k] = f2{0,0}; a1[k] = f2{0,0}; a2[k] = f2{0,0}; }

    const int mbase = half * HNLS;
    #pragma unroll 8
    for (int mm = 0; mm < HNLS; ++mm) {
        int m = mbase + mm;
        float2 q0 = sT[m * 3 + 0];                 // {hx,hy}  (wave-uniform addr)
        float2 q1 = sT[m * 3 + 1];                 // {hz,e0}
        float2 q2 = sT[m * 3 + 2];                 // {e1,e2}
        f2 hx2 = {q0.x, q0.x}, hy2 = {q0.y, q0.y}, hz2 = {q1.x, q1.x};
        f2 e02 = {q1.y, q1.y}, e12 = {q2.x, q2.x}, e22 = {q2.y, q2.y};

        #pragma unroll
        for (int k = 0; k < 2; ++k) {
            f2 s = __builtin_elementwise_fma(nx2[k], hx2,
                   __builtin_elementwise_fma(ny2[k], hy2, nz2[k] * hz2));
            float sx = fmaxf(s.x, 0.0f);           // relu
            float sy = fmaxf(s.y, 0.0f);
            mx = fmaxf(mx, fmaxf(sx, sy));         // -> v_max3_f32
            f2 r = {sx, sy};
            f2 r2  = r * r;
            f2 r4  = r2 * r2;
            f2 r8  = r4 * r4;
            f2 r16 = r8 * r8;
            f2 r32 = r16 * r16;
            f2 r64 = r32 * r32;
            a0[k] = __builtin_elementwise_fma(r64, e02, a0[k]);
            a1[k] = __builtin_elementwise_fma(r64, e12, a1[k]);
            a2[k] = __builtin_elementwise_fma(r64, e22, a2[k]);
        }
    }

    // wave-64 max reduce (covers both halves via the 4 waves)
    #pragma unroll
    for (int off = 32; off > 0; off >>= 1)
        mx = fmaxf(mx, __shfl_xor(mx, off));
    int wid = tid >> 6;
    if ((tid & 63) == 0) swmax[wid] = mx;

    // upper half deposits its partial sums
    if (half) {
        float* dst = &sMerge[li * 13];
        dst[0]  = a0[0].x; dst[1]  = a0[0].y; dst[2]  = a0[1].x; dst[3]  = a0[1].y;
        dst[4]  = a1[0].x; dst[5]  = a1[0].y; dst[6]  = a1[1].x; dst[7]  = a1[1].y;
        dst[8]  = a2[0].x; dst[9]  = a2[0].y; dst[10] = a2[1].x; dst[11] = a2[1].y;
    }
    __syncthreads();

    if (tid == 0) {
        float bm = fmaxf(fmaxf(swmax[0], swmax[1]), fmaxf(swmax[2], swmax[3]));
        atomicMax(maxslot, __float_as_uint(bm));   // f32 >= 0: bit-monotone
    }

    if (!half) {
        const float* src = &sMerge[li * 13];
        a0[0].x += src[0];  a0[0].y += src[1];  a0[1].x += src[2];  a0[1].y += src[3];
        a1[0].x += src[4];  a1[0].y += src[5];  a1[1].x += src[6];  a1[1].y += src[7];
        a2[0].x += src[8];  a2[0].y += src[9];  a2[1].x += src[10]; a2[1].y += src[11];

        // unnormalized sums to out[b][c][h][w]; finalize scales by (1/max)^64
        float* ob = out + (size_t)b * 3 * HWPX;
        #pragma unroll
        for (int k = 0; k < PXPT; ++k) {
            int p = base_in_b + k * 128;
            f2 v0 = a0[k >> 1], v1 = a1[k >> 1], v2 = a2[k >> 1];
            int h = k & 1;
            ob[0 * HWPX + p] = v0[h];
            ob[1 * HWPX + p] = v1[h];
            ob[2 * HWPX + p] = v2[h];
        }
    }
}

__global__ __launch_bounds__(256) void k_finalize(float* __restrict__ out,
                                                  const unsigned* __restrict__ maxslot) {
    float im  = 1.0f / __uint_as_float(*maxslot);   // uniform scalar load
    float i2  = im * im;
    float i4  = i2 * i2;
    float i8  = i4 * i4;
    float i16 = i8 * i8;
    float i32 = i16 * i16;
    float scl = i32 * i32;                          // (1/max)^64
    int i = blockIdx.x * 256 + (int)threadIdx.x;    // over float4s
    float4* o = reinterpret_cast<float4*>(out);
    float4 v = o[i];
    v.x *= scl; v.y *= scl; v.z *= scl; v.w *= scl;
    o[i] = v;
}

extern "C" void kernel_launch(void* const* d_in, const int* in_sizes, int n_in,
                              void* d_out, int out_size, void* d_ws, size_t ws_size,
                              hipStream_t stream) {
    const float* env    = (const float*)d_in[0];   // (B,16,32,3) f32
    const float* normal = (const float*)d_in[1];   // (B,512,512,3) f32
    float* out = (float*)d_out;                    // (B,3,512,512) f32

    char* ws = (char*)d_ws;
    unsigned* maxslot = (unsigned*)ws;
    float2* tab = (float2*)(ws + 256);

    int nblocks = (NB * HWPX) / (128 * PXPT);      // 1024
    int fblocks = (NB * 3 * HWPX) / (4 * 256);     // 1536 (float4 granularity)

    hipLaunchKernelGGL(k_setup, dim3(1), dim3(NL), 0, stream, env, tab, maxslot);
    hipLaunchKernelGGL(k_fused, dim3(nblocks), dim3(256), 0, stream, normal, tab, out, maxslot);
    hipLaunchKernelGGL(k_finalize, dim3(fblocks), dim3(256), 0, stream, out, maxslot);
}